// Round 6
// baseline (523.096 us; speedup 1.0000x reference)
//
#include <hip/hip_runtime.h>

typedef unsigned short u16;
typedef unsigned int u32;
typedef short bf16x8 __attribute__((ext_vector_type(8)));
typedef float f32x4 __attribute__((ext_vector_type(4)));
typedef unsigned short u16x8 __attribute__((ext_vector_type(8)));
typedef unsigned short u16x4 __attribute__((ext_vector_type(4)));

#define DEVFN static __device__ __forceinline__

DEVFN u16 f2b(float f) {
    u32 u = __builtin_bit_cast(u32, f);
    u += 0x7FFFu + ((u >> 16) & 1u);
    return (u16)(u >> 16);
}
DEVFN float b2f(u16 h) {
    u32 u = ((u32)h) << 16;
    return __builtin_bit_cast(float, u);
}

// ---------------------------------------------------------------- prep ----
__global__ void k_prep(const float* __restrict__ qkvw, const float* __restrict__ pjw,
                       u16* __restrict__ qkvwb, u16* __restrict__ pjwb) {
    int id = blockIdx.x * 256 + threadIdx.x;
    if (id < 196608) qkvwb[id] = f2b(qkvw[id]);
    if (id < 65536)  pjwb[id]  = f2b(pjw[id]);
}

__global__ void k_cpb(const float* __restrict__ w1, const float* __restrict__ b1,
                      const float* __restrict__ w2, float* __restrict__ bt) {
    int p = threadIdx.x;
    if (p >= 225) return;
    int d0 = p / 15, d1 = p % 15;
    float v0 = (float)(d0 - 7) * (8.0f / 7.0f);
    float v1 = (float)(d1 - 7) * (8.0f / 7.0f);
    float t0 = copysignf(log2f(fabsf(v0) + 1.0f) * (1.0f / 3.0f), v0);
    float t1 = copysignf(log2f(fabsf(v1) + 1.0f) * (1.0f / 3.0f), v1);
    float s[8] = {0.f, 0.f, 0.f, 0.f, 0.f, 0.f, 0.f, 0.f};
    for (int d = 0; d < 256; ++d) {
        float h = t0 * w1[2 * d] + t1 * w1[2 * d + 1] + b1[d];
        h = fmaxf(h, 0.0f);
        #pragma unroll
        for (int hh = 0; hh < 8; ++hh) s[hh] += h * w2[hh * 256 + d];
    }
    #pragma unroll
    for (int hh = 0; hh < 8; ++hh) bt[p * 8 + hh] = s[hh];
}

__global__ void k_bias(const float* __restrict__ bt, float* __restrict__ bias) {
    int id = blockIdx.x * 256 + threadIdx.x;  // 4096 = 64*64, i=q row, j=k col
    int i = id >> 6, j = id & 63;
    int d0 = (i >> 3) - (j >> 3) + 7;
    int d1 = (i & 7) - (j & 7) + 7;
    int p = d0 * 15 + d1;
    #pragma unroll
    for (int h = 0; h < 8; ++h)
        bias[h * 4096 + id] = 16.0f / (1.0f + expf(-bt[p * 8 + h]));
}

// ---------------------------------------------------------------- qkv -----
// Row-structured GEMM, operand-swapped MFMA: D[och][tok] so each thread
// holds 4 consecutive och per token -> vectorized u16x4 stores, cheap norm.
__global__ __launch_bounds__(256, 4) void k_qkv(
    const float* __restrict__ x, const u16* __restrict__ qkvw,
    const float* __restrict__ qkvb,
    u16* __restrict__ gq, u16* __restrict__ gk, u16* __restrict__ wv_g) {
    __shared__ __align__(16) u16 Xs[2][8192];  // [128 tok][64 ch] swizzled

    // XCD-aware job mapping: all 6 (which,half) blocks of a row on one XCD.
    const int bid = blockIdx.x;                 // 6144 = 8 xcd * 128 rowblk * 6 ny
    const int xcd = bid & 7;
    const int idx = bid >> 3;                   // 0..767
    const int ny = idx % 6;
    const int rowblk = xcd * 128 + idx / 6;     // 0..1023
    const int b = rowblk >> 7, row = rowblk & 127;
    const int which = ny >> 1, half = ny & 1;

    const int tid = threadIdx.x;
    const int wave = tid >> 6, l = tid & 63, col = l & 15, quad = l >> 4;
    const int th = wave >> 1;                   // token half (64 tok)
    const int oq = wave & 1;                    // och quarter
    const int obase = half * 128 + oq * 64;     // och base within `which` (0..255)

    // weight rows for this wave's 4 n-tiles (original qkvw layout)
    int orow[4];
    #pragma unroll
    for (int nt = 0; nt < 4; ++nt) {
        const int oo = obase + nt * 16 + col;   // 0..255 within which
        orow[nt] = (oo >> 5) * 96 + which * 32 + (oo & 31);
    }

    const int tc = tid >> 5;                    // 0..7: 8-ch sub-chunk
    const int tw = (tid & 31) * 4;              // token base (4 consecutive)
    const float* xbase = x + ((size_t)b * 256 * 128 + row) * 128;

    f32x4 acc[4][4];                            // [nt(och)][mt(tok)]
    #pragma unroll
    for (int i = 0; i < 4; ++i)
        #pragma unroll
        for (int j = 0; j < 4; ++j) acc[i][j] = f32x4{0.f, 0.f, 0.f, 0.f};

    float4 st[8];
    auto stage_load = [&](int c) {
        #pragma unroll
        for (int j = 0; j < 8; ++j)
            st[j] = *(const float4*)(xbase + (size_t)(c * 64 + tc * 8 + j) * 16384 + tw);
    };
    // transpose via named members only (no address-of-register casts -> no spill)
    auto stage_write = [&](int buf) {
        u16x8 v0, v1, v2, v3;
        #pragma unroll
        for (int j = 0; j < 8; ++j) {
            v0[j] = f2b(st[j].x);
            v1[j] = f2b(st[j].y);
            v2[j] = f2b(st[j].z);
            v3[j] = f2b(st[j].w);
        }
        const int base7 = tid & 31;             // (tw+i)>>2 for i<4
        const int s0 = tc ^ ((base7 ^ (tw + 0)) & 7);
        const int s1 = tc ^ ((base7 ^ (tw + 1)) & 7);
        const int s2 = tc ^ ((base7 ^ (tw + 2)) & 7);
        const int s3 = tc ^ ((base7 ^ (tw + 3)) & 7);
        *(u16x8*)&Xs[buf][(tw + 0) * 64 + (s0 << 3)] = v0;
        *(u16x8*)&Xs[buf][(tw + 1) * 64 + (s1 << 3)] = v1;
        *(u16x8*)&Xs[buf][(tw + 2) * 64 + (s2 << 3)] = v2;
        *(u16x8*)&Xs[buf][(tw + 3) * 64 + (s3 << 3)] = v3;
    };
    auto gemm = [&](int c, int buf) {
        #pragma unroll
        for (int kk = 0; kk < 2; ++kk) {
            const int cb = c * 64 + kk * 32 + quad * 8;   // global ch base
            const int lchunk = kk * 4 + quad;             // local 8-ch chunk
            bf16x8 bw[4];
            #pragma unroll
            for (int nt = 0; nt < 4; ++nt)
                bw[nt] = *(const bf16x8*)&qkvw[(size_t)orow[nt] * 256 + cb];
            bf16x8 af[4];
            #pragma unroll
            for (int mt = 0; mt < 4; ++mt) {
                const int tok = th * 64 + mt * 16 + col;
                const int slot = lchunk ^ (((tok >> 2) ^ tok) & 7);
                af[mt] = *(const bf16x8*)&Xs[buf][tok * 64 + (slot << 3)];
            }
            // operand swap: A = weights (och rows), B = X (tok cols)
            #pragma unroll
            for (int nt = 0; nt < 4; ++nt)
                #pragma unroll
                for (int mt = 0; mt < 4; ++mt)
                    acc[nt][mt] = __builtin_amdgcn_mfma_f32_16x16x32_bf16(
                        bw[nt], af[mt], acc[nt][mt], 0, 0, 0);
        }
    };

    stage_load(0);
    stage_write(0);
    __syncthreads();
    for (int c = 0; c < 4; ++c) {
        if (c < 3) stage_load(c + 1);      // issue early (T14)
        gemm(c, c & 1);
        if (c < 3) stage_write((c + 1) & 1);  // write late
        __syncthreads();
    }

    // epilogue: D[och][tok]; och = obase + nt*16 + quad*4 + r, tok = th*64+mt*16+col
    const int hA = obase >> 5;
    f32x4 bqv[4];
    #pragma unroll
    for (int nt = 0; nt < 4; ++nt) {
        const int oo = obase + nt * 16 + quad * 4;
        bqv[nt] = *(const f32x4*)&qkvb[(oo >> 5) * 96 + which * 32 + (oo & 31)];
    }
    #pragma unroll
    for (int mt = 0; mt < 4; ++mt) {
        const int tok = th * 64 + mt * 16 + col;
        const int win = b * 256 + (row >> 3) * 16 + (tok >> 3);
        const int tk = (row & 7) * 8 + (tok & 7);
        float v[4][4];
        #pragma unroll
        for (int nt = 0; nt < 4; ++nt)
            #pragma unroll
            for (int r = 0; r < 4; ++r)
                v[nt][r] = acc[nt][mt][r] + bqv[nt][r];
        if (which < 2) {
            float sA = 0.f, sB = 0.f;
            #pragma unroll
            for (int r = 0; r < 4; ++r) {
                sA += v[0][r] * v[0][r] + v[1][r] * v[1][r];
                sB += v[2][r] * v[2][r] + v[3][r] * v[3][r];
            }
            sA += __shfl_xor(sA, 16, 64);
            sA += __shfl_xor(sA, 32, 64);
            sB += __shfl_xor(sB, 16, 64);
            sB += __shfl_xor(sB, 32, 64);
            const float iA = 1.0f / fmaxf(sqrtf(sA), 1e-12f);
            const float iB = 1.0f / fmaxf(sqrtf(sB), 1e-12f);
            #pragma unroll
            for (int r = 0; r < 4; ++r) {
                v[0][r] *= iA; v[1][r] *= iA;
                v[2][r] *= iB; v[3][r] *= iB;
            }
        }
        #pragma unroll
        for (int nt = 0; nt < 4; ++nt) {
            u16x4 ov;
            #pragma unroll
            for (int r = 0; r < 4; ++r) ov[r] = f2b(v[nt][r]);
            if (which == 2) {
                *(u16x4*)&wv_g[((size_t)win * 64 + tk) * 256 + obase + nt * 16 + quad * 4] = ov;
            } else {
                u16* G = (which == 0) ? gq : gk;
                const int h = hA + (nt >> 1);
                const int d = (nt & 1) * 16 + quad * 4;
                *(u16x4*)&G[((size_t)(win * 8 + h) * 64 + tk) * 32 + d] = ov;
            }
        }
    }
}

// ---------------------------------------------------------------- attn ----
// One wave = one (win, head); 4 jobs per block. PV operand-swapped so the
// wout store is a u16x4 per (dt,qt).
__global__ __launch_bounds__(256, 3) void k_attn3(
    const u16* __restrict__ gq, const u16* __restrict__ gk,
    const u16* __restrict__ wv_g,
    const float* __restrict__ lsc, const float* __restrict__ bias,
    u16* __restrict__ wout_g) {
    __shared__ __align__(16) u16 scr[4][6144];  // per wave: v_t[2048] | p_s[4096]

    const int tid = threadIdx.x;
    const int wave = tid >> 6, l = tid & 63, col = l & 15, quad = l >> 4;
    const int job = blockIdx.x * 4 + wave;
    const int h = job >> 11, win = job & 2047;
    u16* const v_t = scr[wave];         // [32 d][64 tok] swz(d&7)
    u16* const p_s = scr[wave] + 2048;  // [64 q][64 k]  swz(i&7)

    #pragma unroll
    for (int it = 0; it < 4; ++it) {
        const int idx = it * 64 + l;
        const int tok = idx & 63, dblk = idx >> 6;
        const u16x8 vv = *(const u16x8*)&wv_g[((size_t)win * 64 + tok) * 256 + h * 32 + dblk * 8];
        #pragma unroll
        for (int j = 0; j < 8; ++j) {
            const int d = dblk * 8 + j;
            v_t[d * 64 + ((((tok >> 3) ^ (d & 7)) << 3) | (tok & 7))] = vv[j];
        }
    }

    const u16* const qbp = gq + (size_t)(win * 8 + h) * 2048;
    const u16* const kbp = gk + (size_t)(win * 8 + h) * 2048;
    bf16x8 aq[4], bk[4];
    #pragma unroll
    for (int mt = 0; mt < 4; ++mt)
        aq[mt] = *(const bf16x8*)&qbp[(mt * 16 + col) * 32 + quad * 8];
    #pragma unroll
    for (int nt = 0; nt < 4; ++nt)
        bk[nt] = *(const bf16x8*)&kbp[(nt * 16 + col) * 32 + quad * 8];

    const f32x4 zero4 = {0.f, 0.f, 0.f, 0.f};
    f32x4 sacc[4][4];
    #pragma unroll
    for (int mt = 0; mt < 4; ++mt)
        #pragma unroll
        for (int nt = 0; nt < 4; ++nt)
            sacc[mt][nt] = __builtin_amdgcn_mfma_f32_16x16x32_bf16(aq[mt], bk[nt], zero4, 0, 0, 0);

    const float ls = expf(fminf(lsc[h], 4.6051701859880914f));
    const float* bh = bias + h * 4096;
    #pragma unroll
    for (int mt = 0; mt < 4; ++mt) {
        #pragma unroll
        for (int r = 0; r < 4; ++r) {
            const int i = mt * 16 + quad * 4 + r;
            float v[4];
            #pragma unroll
            for (int nt = 0; nt < 4; ++nt)
                v[nt] = sacc[mt][nt][r] * ls + bh[i * 64 + nt * 16 + col];
            float mx = fmaxf(fmaxf(v[0], v[1]), fmaxf(v[2], v[3]));
            #pragma unroll
            for (int m = 1; m < 16; m <<= 1) mx = fmaxf(mx, __shfl_xor(mx, m, 64));
            float s = 0.f;
            #pragma unroll
            for (int nt = 0; nt < 4; ++nt) { v[nt] = expf(v[nt] - mx); s += v[nt]; }
            #pragma unroll
            for (int m = 1; m < 16; m <<= 1) s += __shfl_xor(s, m, 64);
            const float inv = 1.0f / s;
            #pragma unroll
            for (int nt = 0; nt < 4; ++nt) sacc[mt][nt][r] = v[nt] * inv;
        }
    }
    #pragma unroll
    for (int mt = 0; mt < 4; ++mt)
        #pragma unroll
        for (int r = 0; r < 4; ++r) {
            const int i = mt * 16 + quad * 4 + r;
            #pragma unroll
            for (int nt = 0; nt < 4; ++nt) {
                const int j = nt * 16 + col;
                p_s[i * 64 + ((((j >> 3) ^ (i & 7)) << 3) | (j & 7))] = f2b(sacc[mt][nt][r]);
            }
        }
    __syncthreads();

    // out^T = V^T P^T via swap: D[d][q]; thread holds 4 consecutive d per q.
    f32x4 oacc[2][4];                    // [dt][qt]
    #pragma unroll
    for (int i = 0; i < 2; ++i)
        #pragma unroll
        for (int j = 0; j < 4; ++j) oacc[i][j] = zero4;
    #pragma unroll
    for (int kk = 0; kk < 2; ++kk) {
        const int kb = kk * 32 + quad * 8;
        bf16x8 ap[4];
        #pragma unroll
        for (int mt = 0; mt < 4; ++mt) {
            const int i = mt * 16 + col;
            ap[mt] = *(const bf16x8*)&p_s[i * 64 + (((kb >> 3) ^ (i & 7)) << 3)];
        }
        bf16x8 bv[2];
        #pragma unroll
        for (int nt = 0; nt < 2; ++nt) {
            const int d = nt * 16 + col;
            bv[nt] = *(const bf16x8*)&v_t[d * 64 + (((kb >> 3) ^ (d & 7)) << 3)];
        }
        #pragma unroll
        for (int dt = 0; dt < 2; ++dt)
            #pragma unroll
            for (int qt = 0; qt < 4; ++qt)
                oacc[dt][qt] = __builtin_amdgcn_mfma_f32_16x16x32_bf16(
                    bv[dt], ap[qt], oacc[dt][qt], 0, 0, 0);
    }
    #pragma unroll
    for (int dt = 0; dt < 2; ++dt)
        #pragma unroll
        for (int qt = 0; qt < 4; ++qt) {
            const int t = qt * 16 + col;
            u16x4 ov;
            #pragma unroll
            for (int r = 0; r < 4; ++r) ov[r] = f2b(oacc[dt][qt][r]);
            *(u16x4*)&wout_g[((size_t)win * 64 + t) * 256 + h * 32 + dt * 16 + quad * 4] = ov;
        }
}

// ---------------------------------------------------------------- proj ----
// Operand-swapped GEMM: D[tok][och] -> direct float4 stores from acc.
__global__ __launch_bounds__(256, 4) void k_proj(
    const u16* __restrict__ wout_g, const u16* __restrict__ wv_g,
    const float* __restrict__ pe_w, const float* __restrict__ pe_b,
    const u16* __restrict__ pjw, const float* __restrict__ pjb,
    float* __restrict__ out) {
    __shared__ __align__(16) u16 y_s[64 * 256];
    const int win = blockIdx.x;
    const int b = win >> 8;
    const int h0 = ((win >> 4) & 15) * 8;
    const int w0 = (win & 15) * 8;
    const int tid = threadIdx.x;
    const int cg = tid & 31, ch = cg * 8;
    const int psub = tid >> 5;

    float pw[9][8];
    #pragma unroll
    for (int j = 0; j < 8; ++j)
        #pragma unroll
        for (int k = 0; k < 9; ++k) pw[k][j] = pe_w[(ch + j) * 9 + k];
    float pb[8];
    #pragma unroll
    for (int j = 0; j < 8; ++j) pb[j] = pe_b[ch + j];

    for (int it = 0; it < 8; ++it) {
        const int p = it * 8 + psub;
        const int gh = h0 + (p >> 3), gw = w0 + (p & 7);
        float a[8];
        {
            const bf16x8 ov = *(const bf16x8*)&wout_g[((size_t)win * 64 + p) * 256 + ch];
            #pragma unroll
            for (int j = 0; j < 8; ++j) a[j] = b2f((u16)ov[j]) + pb[j];
        }
        #pragma unroll
        for (int dy = -1; dy <= 1; ++dy)
            #pragma unroll
            for (int dx = -1; dx <= 1; ++dx) {
                const int hh = gh + dy, ww2 = gw + dx;
                if (hh < 0 || hh >= 128 || ww2 < 0 || ww2 >= 128) continue;
                const int nwin = b * 256 + (hh >> 3) * 16 + (ww2 >> 3);
                const int ntk = (hh & 7) * 8 + (ww2 & 7);
                const bf16x8 vv = *(const bf16x8*)&wv_g[((size_t)nwin * 64 + ntk) * 256 + ch];
                const int k = (dy + 1) * 3 + (dx + 1);
                #pragma unroll
                for (int j = 0; j < 8; ++j) a[j] += b2f((u16)vv[j]) * pw[k][j];
            }
        u16x8 tmp;
        #pragma unroll
        for (int j = 0; j < 8; ++j) tmp[j] = f2b(a[j]);
        *(u16x8*)&y_s[p * 256 + (((ch >> 3) ^ (p & 7)) << 3)] = tmp;
    }
    __syncthreads();

    const int wave = tid >> 6, l = tid & 63;
    const int col = l & 15, quad = l >> 4;
    const f32x4 zero4 = {0.f, 0.f, 0.f, 0.f};
    f32x4 macc[4][4];                    // [pt(tok)][ot(och)]
    #pragma unroll
    for (int pt = 0; pt < 4; ++pt)
        #pragma unroll
        for (int ot = 0; ot < 4; ++ot) macc[pt][ot] = zero4;
    const int ob = wave * 64;
    for (int kk = 0; kk < 8; ++kk) {
        const int cb = kk * 32 + quad * 8;
        bf16x8 aw[4], by[4];
        #pragma unroll
        for (int ot = 0; ot < 4; ++ot)
            aw[ot] = *(const bf16x8*)&pjw[(size_t)(ob + ot * 16 + col) * 256 + cb];
        #pragma unroll
        for (int pt = 0; pt < 4; ++pt) {
            const int p = pt * 16 + col;
            by[pt] = *(const bf16x8*)&y_s[p * 256 + (((cb >> 3) ^ (p & 7)) << 3)];
        }
        // operand swap: A = y tokens, B = proj weights -> D[tok][och]
        #pragma unroll
        for (int pt = 0; pt < 4; ++pt)
            #pragma unroll
            for (int ot = 0; ot < 4; ++ot)
                macc[pt][ot] = __builtin_amdgcn_mfma_f32_16x16x32_bf16(
                    by[pt], aw[ot], macc[pt][ot], 0, 0, 0);
    }
    #pragma unroll
    for (int ot = 0; ot < 4; ++ot) {
        const int o = ob + ot * 16 + col;
        const float pbv = pjb[o];
        #pragma unroll
        for (int pt = 0; pt < 4; ++pt) {
            const int p0 = pt * 16 + quad * 4;   // 4 consecutive tokens, same wrow
            float4 ov;
            ov.x = macc[pt][ot][0] + pbv;
            ov.y = macc[pt][ot][1] + pbv;
            ov.z = macc[pt][ot][2] + pbv;
            ov.w = macc[pt][ot][3] + pbv;
            *(float4*)&out[((size_t)(b * 256 + o)) * 16384 +
                           (h0 + (p0 >> 3)) * 128 + w0 + (p0 & 7)] = ov;
        }
    }
}

// -------------------------------------------------------------- launch ----
extern "C" void kernel_launch(void* const* d_in, const int* in_sizes, int n_in,
                              void* d_out, int out_size, void* d_ws, size_t ws_size,
                              hipStream_t stream) {
    const float* x    = (const float*)d_in[0];
    const float* qkvw = (const float*)d_in[1];
    const float* qkvb = (const float*)d_in[2];
    const float* pjw  = (const float*)d_in[3];
    const float* pjb  = (const float*)d_in[4];
    const float* pew  = (const float*)d_in[5];
    const float* peb  = (const float*)d_in[6];
    const float* lsc  = (const float*)d_in[7];
    const float* w1   = (const float*)d_in[8];
    const float* b1   = (const float*)d_in[9];
    const float* w2   = (const float*)d_in[10];

    char* ws = (char*)d_ws;
    u16* wv_b    = (u16*)(ws);                                    // 64 MiB
    u16* wout_b  = (u16*)(ws + (64ull << 20));                    // 64 MiB
    u16* qkvwb   = (u16*)(ws + (128ull << 20));                   // 384 KiB
    u16* pjwb    = (u16*)(ws + (128ull << 20) + 393216);          // 128 KiB
    float* bias  = (float*)(ws + (128ull << 20) + 393216 + 131072); // 128 KiB
    float* bt    = (float*)(ws + (128ull << 20) + 393216 + 262144); // 7.2 KiB

    // q/k scratch lives inside d_out (134.2 MB = exactly 2 x 64 MiB bf16);
    // dead before k_proj fully overwrites d_out.
    u16* gq = (u16*)d_out;
    u16* gk = gq + 33554432u;

    hipLaunchKernelGGL(k_prep, dim3(768), dim3(256), 0, stream, qkvw, pjw, qkvwb, pjwb);
    hipLaunchKernelGGL(k_cpb,  dim3(1),   dim3(256), 0, stream, w1, b1, w2, bt);
    hipLaunchKernelGGL(k_bias, dim3(16),  dim3(256), 0, stream, bt, bias);
    hipLaunchKernelGGL(k_qkv,  dim3(6144), dim3(256), 0, stream,
                       x, qkvwb, qkvb, gq, gk, wv_b);
    hipLaunchKernelGGL(k_attn3, dim3(4096), dim3(256), 0, stream,
                       gq, gk, wv_b, lsc, bias, wout_b);
    hipLaunchKernelGGL(k_proj, dim3(2048), dim3(256), 0, stream,
                       wout_b, wv_b, pew, peb, pjwb, pjb, (float*)d_out);
}

// Round 7
// 449.438 us; speedup vs baseline: 1.1639x; 1.1639x over previous
//
#include <hip/hip_runtime.h>

typedef unsigned short u16;
typedef unsigned int u32;
typedef short bf16x8 __attribute__((ext_vector_type(8)));
typedef float f32x4 __attribute__((ext_vector_type(4)));
typedef unsigned short u16x8 __attribute__((ext_vector_type(8)));
typedef unsigned short u16x4 __attribute__((ext_vector_type(4)));

#define DEVFN static __device__ __forceinline__

DEVFN u16 f2b(float f) {
    u32 u = __builtin_bit_cast(u32, f);
    u += 0x7FFFu + ((u >> 16) & 1u);
    return (u16)(u >> 16);
}
DEVFN float b2f(u16 h) {
    u32 u = ((u32)h) << 16;
    return __builtin_bit_cast(float, u);
}

// ---------------------------------------------------------------- prep ----
__global__ void k_prep(const float* __restrict__ qkvw, const float* __restrict__ pjw,
                       u16* __restrict__ qkvwb, u16* __restrict__ pjwb) {
    int id = blockIdx.x * 256 + threadIdx.x;
    if (id < 196608) qkvwb[id] = f2b(qkvw[id]);
    if (id < 65536)  pjwb[id]  = f2b(pjw[id]);
}

__global__ void k_cpb(const float* __restrict__ w1, const float* __restrict__ b1,
                      const float* __restrict__ w2, float* __restrict__ bt) {
    int p = threadIdx.x;
    if (p >= 225) return;
    int d0 = p / 15, d1 = p % 15;
    float v0 = (float)(d0 - 7) * (8.0f / 7.0f);
    float v1 = (float)(d1 - 7) * (8.0f / 7.0f);
    float t0 = copysignf(log2f(fabsf(v0) + 1.0f) * (1.0f / 3.0f), v0);
    float t1 = copysignf(log2f(fabsf(v1) + 1.0f) * (1.0f / 3.0f), v1);
    float s[8] = {0.f, 0.f, 0.f, 0.f, 0.f, 0.f, 0.f, 0.f};
    for (int d = 0; d < 256; ++d) {
        float h = t0 * w1[2 * d] + t1 * w1[2 * d + 1] + b1[d];
        h = fmaxf(h, 0.0f);
        #pragma unroll
        for (int hh = 0; hh < 8; ++hh) s[hh] += h * w2[hh * 256 + d];
    }
    #pragma unroll
    for (int hh = 0; hh < 8; ++hh) bt[p * 8 + hh] = s[hh];
}

__global__ void k_bias(const float* __restrict__ bt, float* __restrict__ bias) {
    int id = blockIdx.x * 256 + threadIdx.x;  // 4096 = 64*64, i=q row, j=k col
    int i = id >> 6, j = id & 63;
    int d0 = (i >> 3) - (j >> 3) + 7;
    int d1 = (i & 7) - (j & 7) + 7;
    int p = d0 * 15 + d1;
    #pragma unroll
    for (int h = 0; h < 8; ++h)
        bias[h * 4096 + id] = 16.0f / (1.0f + expf(-bt[p * 8 + h]));
}

// ---------------------------------------------------------------- qkv -----
// Row-structured GEMM, operand-swapped MFMA: D[och][tok].
// __launch_bounds__(256,3): VGPR cap ~170. (256,4)'s 128 cap provably spills
// (R4: VGPR=64/WRITE 412MB; R6: VGPR=64/WRITE 338MB) -> keep 3.
__global__ __launch_bounds__(256, 3) void k_qkv(
    const float* __restrict__ x, const u16* __restrict__ qkvw,
    const float* __restrict__ qkvb,
    u16* __restrict__ gq, u16* __restrict__ gk, u16* __restrict__ wv_g) {
    __shared__ __align__(16) u16 Xs[2][8192];  // [128 tok][64 ch] swizzled

    // XCD-aware job mapping: all 6 (which,half) blocks of a row on one XCD.
    const int bid = blockIdx.x;                 // 6144 = 8 xcd * 128 rowblk * 6 ny
    const int xcd = bid & 7;
    const int idx = bid >> 3;                   // 0..767
    const int ny = idx % 6;
    const int rowblk = xcd * 128 + idx / 6;     // 0..1023
    const int b = rowblk >> 7, row = rowblk & 127;
    const int which = ny >> 1, half = ny & 1;

    const int tid = threadIdx.x;
    const int wave = tid >> 6, l = tid & 63, col = l & 15, quad = l >> 4;
    const int th = wave >> 1;                   // token half (64 tok)
    const int oq = wave & 1;                    // och quarter
    const int obase = half * 128 + oq * 64;     // och base within `which` (0..255)

    // weight rows for this wave's 4 n-tiles (original qkvw layout)
    int orow[4];
    #pragma unroll
    for (int nt = 0; nt < 4; ++nt) {
        const int oo = obase + nt * 16 + col;   // 0..255 within which
        orow[nt] = (oo >> 5) * 96 + which * 32 + (oo & 31);
    }

    const int tc = tid >> 5;                    // 0..7: 8-ch sub-chunk
    const int tw = (tid & 31) * 4;              // token base (4 consecutive)
    const float* xbase = x + ((size_t)b * 256 * 128 + row) * 128;

    f32x4 acc[4][4];                            // [nt(och)][mt(tok)]
    #pragma unroll
    for (int i = 0; i < 4; ++i)
        #pragma unroll
        for (int j = 0; j < 4; ++j) acc[i][j] = f32x4{0.f, 0.f, 0.f, 0.f};

    float4 st[8];
    auto stage_load = [&](int c) {
        #pragma unroll
        for (int j = 0; j < 8; ++j)
            st[j] = *(const float4*)(xbase + (size_t)(c * 64 + tc * 8 + j) * 16384 + tw);
    };
    // transpose via named members only (no address-of-register casts -> no spill)
    auto stage_write = [&](int buf) {
        u16x8 v0, v1, v2, v3;
        #pragma unroll
        for (int j = 0; j < 8; ++j) {
            v0[j] = f2b(st[j].x);
            v1[j] = f2b(st[j].y);
            v2[j] = f2b(st[j].z);
            v3[j] = f2b(st[j].w);
        }
        const int base7 = tid & 31;             // (tw+i)>>2 for i<4
        const int s0 = tc ^ ((base7 ^ (tw + 0)) & 7);
        const int s1 = tc ^ ((base7 ^ (tw + 1)) & 7);
        const int s2 = tc ^ ((base7 ^ (tw + 2)) & 7);
        const int s3 = tc ^ ((base7 ^ (tw + 3)) & 7);
        *(u16x8*)&Xs[buf][(tw + 0) * 64 + (s0 << 3)] = v0;
        *(u16x8*)&Xs[buf][(tw + 1) * 64 + (s1 << 3)] = v1;
        *(u16x8*)&Xs[buf][(tw + 2) * 64 + (s2 << 3)] = v2;
        *(u16x8*)&Xs[buf][(tw + 3) * 64 + (s3 << 3)] = v3;
    };
    auto gemm = [&](int c, int buf) {
        #pragma unroll
        for (int kk = 0; kk < 2; ++kk) {
            const int cb = c * 64 + kk * 32 + quad * 8;   // global ch base
            const int lchunk = kk * 4 + quad;             // local 8-ch chunk
            bf16x8 bw[4];
            #pragma unroll
            for (int nt = 0; nt < 4; ++nt)
                bw[nt] = *(const bf16x8*)&qkvw[(size_t)orow[nt] * 256 + cb];
            bf16x8 af[4];
            #pragma unroll
            for (int mt = 0; mt < 4; ++mt) {
                const int tok = th * 64 + mt * 16 + col;
                const int slot = lchunk ^ (((tok >> 2) ^ tok) & 7);
                af[mt] = *(const bf16x8*)&Xs[buf][tok * 64 + (slot << 3)];
            }
            // operand swap: A = weights (och rows), B = X (tok cols)
            #pragma unroll
            for (int nt = 0; nt < 4; ++nt)
                #pragma unroll
                for (int mt = 0; mt < 4; ++mt)
                    acc[nt][mt] = __builtin_amdgcn_mfma_f32_16x16x32_bf16(
                        bw[nt], af[mt], acc[nt][mt], 0, 0, 0);
        }
    };

    stage_load(0);
    stage_write(0);
    __syncthreads();
    for (int c = 0; c < 4; ++c) {
        if (c < 3) stage_load(c + 1);      // issue early (T14)
        gemm(c, c & 1);
        if (c < 3) stage_write((c + 1) & 1);  // write late
        __syncthreads();
    }

    // epilogue: D[och][tok]; och = obase + nt*16 + quad*4 + r, tok = th*64+mt*16+col
    const int hA = obase >> 5;
    f32x4 bqv[4];
    #pragma unroll
    for (int nt = 0; nt < 4; ++nt) {
        const int oo = obase + nt * 16 + quad * 4;
        bqv[nt] = *(const f32x4*)&qkvb[(oo >> 5) * 96 + which * 32 + (oo & 31)];
    }
    #pragma unroll
    for (int mt = 0; mt < 4; ++mt) {
        const int tok = th * 64 + mt * 16 + col;
        const int win = b * 256 + (row >> 3) * 16 + (tok >> 3);
        const int tk = (row & 7) * 8 + (tok & 7);
        float v[4][4];
        #pragma unroll
        for (int nt = 0; nt < 4; ++nt)
            #pragma unroll
            for (int r = 0; r < 4; ++r)
                v[nt][r] = acc[nt][mt][r] + bqv[nt][r];
        if (which < 2) {
            float sA = 0.f, sB = 0.f;
            #pragma unroll
            for (int r = 0; r < 4; ++r) {
                sA += v[0][r] * v[0][r] + v[1][r] * v[1][r];
                sB += v[2][r] * v[2][r] + v[3][r] * v[3][r];
            }
            sA += __shfl_xor(sA, 16, 64);
            sA += __shfl_xor(sA, 32, 64);
            sB += __shfl_xor(sB, 16, 64);
            sB += __shfl_xor(sB, 32, 64);
            const float iA = 1.0f / fmaxf(sqrtf(sA), 1e-12f);
            const float iB = 1.0f / fmaxf(sqrtf(sB), 1e-12f);
            #pragma unroll
            for (int r = 0; r < 4; ++r) {
                v[0][r] *= iA; v[1][r] *= iA;
                v[2][r] *= iB; v[3][r] *= iB;
            }
        }
        #pragma unroll
        for (int nt = 0; nt < 4; ++nt) {
            u16x4 ov;
            #pragma unroll
            for (int r = 0; r < 4; ++r) ov[r] = f2b(v[nt][r]);
            if (which == 2) {
                *(u16x4*)&wv_g[((size_t)win * 64 + tk) * 256 + obase + nt * 16 + quad * 4] = ov;
            } else {
                u16* G = (which == 0) ? gq : gk;
                const int h = hA + (nt >> 1);
                const int d = (nt & 1) * 16 + quad * 4;
                *(u16x4*)&G[((size_t)(win * 8 + h) * 64 + tk) * 32 + d] = ov;
            }
        }
    }
}

// ---------------------------------------------------------------- attn ----
// One wave = one (win, head); 4 jobs per block. PV operand-swapped so the
// wout store is a u16x4 per (dt,qt).
__global__ __launch_bounds__(256, 3) void k_attn3(
    const u16* __restrict__ gq, const u16* __restrict__ gk,
    const u16* __restrict__ wv_g,
    const float* __restrict__ lsc, const float* __restrict__ bias,
    u16* __restrict__ wout_g) {
    __shared__ __align__(16) u16 scr[4][6144];  // per wave: v_t[2048] | p_s[4096]

    const int tid = threadIdx.x;
    const int wave = tid >> 6, l = tid & 63, col = l & 15, quad = l >> 4;
    const int job = blockIdx.x * 4 + wave;
    const int h = job >> 11, win = job & 2047;
    u16* const v_t = scr[wave];         // [32 d][64 tok] swz(d&7)
    u16* const p_s = scr[wave] + 2048;  // [64 q][64 k]  swz(i&7)

    #pragma unroll
    for (int it = 0; it < 4; ++it) {
        const int idx = it * 64 + l;
        const int tok = idx & 63, dblk = idx >> 6;
        const u16x8 vv = *(const u16x8*)&wv_g[((size_t)win * 64 + tok) * 256 + h * 32 + dblk * 8];
        #pragma unroll
        for (int j = 0; j < 8; ++j) {
            const int d = dblk * 8 + j;
            v_t[d * 64 + ((((tok >> 3) ^ (d & 7)) << 3) | (tok & 7))] = vv[j];
        }
    }

    const u16* const qbp = gq + (size_t)(win * 8 + h) * 2048;
    const u16* const kbp = gk + (size_t)(win * 8 + h) * 2048;
    bf16x8 aq[4], bk[4];
    #pragma unroll
    for (int mt = 0; mt < 4; ++mt)
        aq[mt] = *(const bf16x8*)&qbp[(mt * 16 + col) * 32 + quad * 8];
    #pragma unroll
    for (int nt = 0; nt < 4; ++nt)
        bk[nt] = *(const bf16x8*)&kbp[(nt * 16 + col) * 32 + quad * 8];

    const f32x4 zero4 = {0.f, 0.f, 0.f, 0.f};
    f32x4 sacc[4][4];
    #pragma unroll
    for (int mt = 0; mt < 4; ++mt)
        #pragma unroll
        for (int nt = 0; nt < 4; ++nt)
            sacc[mt][nt] = __builtin_amdgcn_mfma_f32_16x16x32_bf16(aq[mt], bk[nt], zero4, 0, 0, 0);

    const float ls = expf(fminf(lsc[h], 4.6051701859880914f));
    const float* bh = bias + h * 4096;
    #pragma unroll
    for (int mt = 0; mt < 4; ++mt) {
        #pragma unroll
        for (int r = 0; r < 4; ++r) {
            const int i = mt * 16 + quad * 4 + r;
            float v[4];
            #pragma unroll
            for (int nt = 0; nt < 4; ++nt)
                v[nt] = sacc[mt][nt][r] * ls + bh[i * 64 + nt * 16 + col];
            float mx = fmaxf(fmaxf(v[0], v[1]), fmaxf(v[2], v[3]));
            #pragma unroll
            for (int m = 1; m < 16; m <<= 1) mx = fmaxf(mx, __shfl_xor(mx, m, 64));
            float s = 0.f;
            #pragma unroll
            for (int nt = 0; nt < 4; ++nt) { v[nt] = expf(v[nt] - mx); s += v[nt]; }
            #pragma unroll
            for (int m = 1; m < 16; m <<= 1) s += __shfl_xor(s, m, 64);
            const float inv = 1.0f / s;
            #pragma unroll
            for (int nt = 0; nt < 4; ++nt) sacc[mt][nt][r] = v[nt] * inv;
        }
    }
    #pragma unroll
    for (int mt = 0; mt < 4; ++mt)
        #pragma unroll
        for (int r = 0; r < 4; ++r) {
            const int i = mt * 16 + quad * 4 + r;
            #pragma unroll
            for (int nt = 0; nt < 4; ++nt) {
                const int j = nt * 16 + col;
                p_s[i * 64 + ((((j >> 3) ^ (i & 7)) << 3) | (j & 7))] = f2b(sacc[mt][nt][r]);
            }
        }
    __syncthreads();

    // out^T = V^T P^T via swap: D[d][q]; thread holds 4 consecutive d per q.
    f32x4 oacc[2][4];                    // [dt][qt]
    #pragma unroll
    for (int i = 0; i < 2; ++i)
        #pragma unroll
        for (int j = 0; j < 4; ++j) oacc[i][j] = zero4;
    #pragma unroll
    for (int kk = 0; kk < 2; ++kk) {
        const int kb = kk * 32 + quad * 8;
        bf16x8 ap[4];
        #pragma unroll
        for (int mt = 0; mt < 4; ++mt) {
            const int i = mt * 16 + col;
            ap[mt] = *(const bf16x8*)&p_s[i * 64 + (((kb >> 3) ^ (i & 7)) << 3)];
        }
        bf16x8 bv[2];
        #pragma unroll
        for (int nt = 0; nt < 2; ++nt) {
            const int d = nt * 16 + col;
            bv[nt] = *(const bf16x8*)&v_t[d * 64 + (((kb >> 3) ^ (d & 7)) << 3)];
        }
        #pragma unroll
        for (int dt = 0; dt < 2; ++dt)
            #pragma unroll
            for (int qt = 0; qt < 4; ++qt)
                oacc[dt][qt] = __builtin_amdgcn_mfma_f32_16x16x32_bf16(
                    bv[dt], ap[qt], oacc[dt][qt], 0, 0, 0);
    }
    #pragma unroll
    for (int dt = 0; dt < 2; ++dt)
        #pragma unroll
        for (int qt = 0; qt < 4; ++qt) {
            const int t = qt * 16 + col;
            u16x4 ov;
            #pragma unroll
            for (int r = 0; r < 4; ++r) ov[r] = f2b(oacc[dt][qt][r]);
            *(u16x4*)&wout_g[((size_t)win * 64 + t) * 256 + h * 32 + dt * 16 + quad * 4] = ov;
        }
}

// ---------------------------------------------------------------- proj ----
// Operand-swapped GEMM: D[tok][och] -> direct float4 stores from acc.
__global__ __launch_bounds__(256, 4) void k_proj(
    const u16* __restrict__ wout_g, const u16* __restrict__ wv_g,
    const float* __restrict__ pe_w, const float* __restrict__ pe_b,
    const u16* __restrict__ pjw, const float* __restrict__ pjb,
    float* __restrict__ out) {
    __shared__ __align__(16) u16 y_s[64 * 256];
    const int win = blockIdx.x;
    const int b = win >> 8;
    const int h0 = ((win >> 4) & 15) * 8;
    const int w0 = (win & 15) * 8;
    const int tid = threadIdx.x;
    const int cg = tid & 31, ch = cg * 8;
    const int psub = tid >> 5;

    float pw[9][8];
    #pragma unroll
    for (int j = 0; j < 8; ++j)
        #pragma unroll
        for (int k = 0; k < 9; ++k) pw[k][j] = pe_w[(ch + j) * 9 + k];
    float pb[8];
    #pragma unroll
    for (int j = 0; j < 8; ++j) pb[j] = pe_b[ch + j];

    for (int it = 0; it < 8; ++it) {
        const int p = it * 8 + psub;
        const int gh = h0 + (p >> 3), gw = w0 + (p & 7);
        float a[8];
        {
            const bf16x8 ov = *(const bf16x8*)&wout_g[((size_t)win * 64 + p) * 256 + ch];
            #pragma unroll
            for (int j = 0; j < 8; ++j) a[j] = b2f((u16)ov[j]) + pb[j];
        }
        #pragma unroll
        for (int dy = -1; dy <= 1; ++dy)
            #pragma unroll
            for (int dx = -1; dx <= 1; ++dx) {
                const int hh = gh + dy, ww2 = gw + dx;
                if (hh < 0 || hh >= 128 || ww2 < 0 || ww2 >= 128) continue;
                const int nwin = b * 256 + (hh >> 3) * 16 + (ww2 >> 3);
                const int ntk = (hh & 7) * 8 + (ww2 & 7);
                const bf16x8 vv = *(const bf16x8*)&wv_g[((size_t)nwin * 64 + ntk) * 256 + ch];
                const int k = (dy + 1) * 3 + (dx + 1);
                #pragma unroll
                for (int j = 0; j < 8; ++j) a[j] += b2f((u16)vv[j]) * pw[k][j];
            }
        u16x8 tmp;
        #pragma unroll
        for (int j = 0; j < 8; ++j) tmp[j] = f2b(a[j]);
        *(u16x8*)&y_s[p * 256 + (((ch >> 3) ^ (p & 7)) << 3)] = tmp;
    }
    __syncthreads();

    const int wave = tid >> 6, l = tid & 63;
    const int col = l & 15, quad = l >> 4;
    const f32x4 zero4 = {0.f, 0.f, 0.f, 0.f};
    f32x4 macc[4][4];                    // [pt(tok)][ot(och)]
    #pragma unroll
    for (int pt = 0; pt < 4; ++pt)
        #pragma unroll
        for (int ot = 0; ot < 4; ++ot) macc[pt][ot] = zero4;
    const int ob = wave * 64;
    for (int kk = 0; kk < 8; ++kk) {
        const int cb = kk * 32 + quad * 8;
        bf16x8 aw[4], by[4];
        #pragma unroll
        for (int ot = 0; ot < 4; ++ot)
            aw[ot] = *(const bf16x8*)&pjw[(size_t)(ob + ot * 16 + col) * 256 + cb];
        #pragma unroll
        for (int pt = 0; pt < 4; ++pt) {
            const int p = pt * 16 + col;
            by[pt] = *(const bf16x8*)&y_s[p * 256 + (((cb >> 3) ^ (p & 7)) << 3)];
        }
        // operand swap: A = y tokens, B = proj weights -> D[tok][och]
        #pragma unroll
        for (int pt = 0; pt < 4; ++pt)
            #pragma unroll
            for (int ot = 0; ot < 4; ++ot)
                macc[pt][ot] = __builtin_amdgcn_mfma_f32_16x16x32_bf16(
                    by[pt], aw[ot], macc[pt][ot], 0, 0, 0);
    }
    #pragma unroll
    for (int ot = 0; ot < 4; ++ot) {
        const int o = ob + ot * 16 + col;
        const float pbv = pjb[o];
        #pragma unroll
        for (int pt = 0; pt < 4; ++pt) {
            const int p0 = pt * 16 + quad * 4;   // 4 consecutive tokens, same wrow
            float4 ov;
            ov.x = macc[pt][ot][0] + pbv;
            ov.y = macc[pt][ot][1] + pbv;
            ov.z = macc[pt][ot][2] + pbv;
            ov.w = macc[pt][ot][3] + pbv;
            *(float4*)&out[((size_t)(b * 256 + o)) * 16384 +
                           (h0 + (p0 >> 3)) * 128 + w0 + (p0 & 7)] = ov;
        }
    }
}

// -------------------------------------------------------------- launch ----
extern "C" void kernel_launch(void* const* d_in, const int* in_sizes, int n_in,
                              void* d_out, int out_size, void* d_ws, size_t ws_size,
                              hipStream_t stream) {
    const float* x    = (const float*)d_in[0];
    const float* qkvw = (const float*)d_in[1];
    const float* qkvb = (const float*)d_in[2];
    const float* pjw  = (const float*)d_in[3];
    const float* pjb  = (const float*)d_in[4];
    const float* pew  = (const float*)d_in[5];
    const float* peb  = (const float*)d_in[6];
    const float* lsc  = (const float*)d_in[7];
    const float* w1   = (const float*)d_in[8];
    const float* b1   = (const float*)d_in[9];
    const float* w2   = (const float*)d_in[10];

    char* ws = (char*)d_ws;
    u16* wv_b    = (u16*)(ws);                                    // 64 MiB
    u16* wout_b  = (u16*)(ws + (64ull << 20));                    // 64 MiB
    u16* qkvwb   = (u16*)(ws + (128ull << 20));                   // 384 KiB
    u16* pjwb    = (u16*)(ws + (128ull << 20) + 393216);          // 128 KiB
    float* bias  = (float*)(ws + (128ull << 20) + 393216 + 131072); // 128 KiB
    float* bt    = (float*)(ws + (128ull << 20) + 393216 + 262144); // 7.2 KiB

    // q/k scratch lives inside d_out (134.2 MB = exactly 2 x 64 MiB bf16);
    // dead before k_proj fully overwrites d_out.
    u16* gq = (u16*)d_out;
    u16* gk = gq + 33554432u;

    hipLaunchKernelGGL(k_prep, dim3(768), dim3(256), 0, stream, qkvw, pjw, qkvwb, pjwb);
    hipLaunchKernelGGL(k_cpb,  dim3(1),   dim3(256), 0, stream, w1, b1, w2, bt);
    hipLaunchKernelGGL(k_bias, dim3(16),  dim3(256), 0, stream, bt, bias);
    hipLaunchKernelGGL(k_qkv,  dim3(6144), dim3(256), 0, stream,
                       x, qkvwb, qkvb, gq, gk, wv_b);
    hipLaunchKernelGGL(k_attn3, dim3(4096), dim3(256), 0, stream,
                       gq, gk, wv_b, lsc, bias, wout_b);
    hipLaunchKernelGGL(k_proj, dim3(2048), dim3(256), 0, stream,
                       wout_b, wv_b, pew, peb, pjwb, pjb, (float*)d_out);
}

// Round 8
// 437.346 us; speedup vs baseline: 1.1961x; 1.0276x over previous
//
#include <hip/hip_runtime.h>

typedef unsigned short u16;
typedef unsigned int u32;
typedef short bf16x8 __attribute__((ext_vector_type(8)));
typedef float f32x4 __attribute__((ext_vector_type(4)));
typedef unsigned short u16x8 __attribute__((ext_vector_type(8)));
typedef unsigned short u16x4 __attribute__((ext_vector_type(4)));

#define DEVFN static __device__ __forceinline__

DEVFN u16 f2b(float f) {
    u32 u = __builtin_bit_cast(u32, f);
    u += 0x7FFFu + ((u >> 16) & 1u);
    return (u16)(u >> 16);
}
DEVFN float b2f(u16 h) {
    u32 u = ((u32)h) << 16;
    return __builtin_bit_cast(float, u);
}

// ---------------------------------------------------------------- prep ----
__global__ void k_prep(const float* __restrict__ qkvw, const float* __restrict__ pjw,
                       u16* __restrict__ qkvwb, u16* __restrict__ pjwb) {
    int id = blockIdx.x * 256 + threadIdx.x;
    if (id < 196608) qkvwb[id] = f2b(qkvw[id]);
    if (id < 65536)  pjwb[id]  = f2b(pjw[id]);
}

__global__ void k_cpb(const float* __restrict__ w1, const float* __restrict__ b1,
                      const float* __restrict__ w2, float* __restrict__ bt) {
    int p = threadIdx.x;
    if (p >= 225) return;
    int d0 = p / 15, d1 = p % 15;
    float v0 = (float)(d0 - 7) * (8.0f / 7.0f);
    float v1 = (float)(d1 - 7) * (8.0f / 7.0f);
    float t0 = copysignf(log2f(fabsf(v0) + 1.0f) * (1.0f / 3.0f), v0);
    float t1 = copysignf(log2f(fabsf(v1) + 1.0f) * (1.0f / 3.0f), v1);
    float s[8] = {0.f, 0.f, 0.f, 0.f, 0.f, 0.f, 0.f, 0.f};
    for (int d = 0; d < 256; ++d) {
        float h = t0 * w1[2 * d] + t1 * w1[2 * d + 1] + b1[d];
        h = fmaxf(h, 0.0f);
        #pragma unroll
        for (int hh = 0; hh < 8; ++hh) s[hh] += h * w2[hh * 256 + d];
    }
    #pragma unroll
    for (int hh = 0; hh < 8; ++hh) bt[p * 8 + hh] = s[hh];
}

// TRANSPOSED bias table: biasT[h][k][q] (for the S^T-layout softmax)
__global__ void k_bias(const float* __restrict__ bt, float* __restrict__ biasT) {
    int id = blockIdx.x * 256 + threadIdx.x;  // id = k*64 + q
    int kq = id >> 6, q = id & 63;
    int d0 = (q >> 3) - (kq >> 3) + 7;
    int d1 = (q & 7) - (kq & 7) + 7;
    int p = d0 * 15 + d1;
    #pragma unroll
    for (int h = 0; h < 8; ++h)
        biasT[h * 4096 + id] = 16.0f / (1.0f + expf(-bt[p * 8 + h]));
}

// ---------------------------------------------------------------- qkv -----
// Row-structured GEMM, operand-swapped MFMA: D[och][tok]; double-buffered
// weight-register prefetch so gemm(c) never waits on L2 weight loads.
__global__ __launch_bounds__(256, 3) void k_qkv(
    const float* __restrict__ x, const u16* __restrict__ qkvw,
    const float* __restrict__ qkvb,
    u16* __restrict__ gq, u16* __restrict__ gk, u16* __restrict__ wv_g) {
    __shared__ __align__(16) u16 Xs[2][8192];  // [128 tok][64 ch] swizzled

    const int bid = blockIdx.x;                 // 6144 = 8 xcd * 128 rowblk * 6 ny
    const int xcd = bid & 7;
    const int idx = bid >> 3;                   // 0..767
    const int ny = idx % 6;
    const int rowblk = xcd * 128 + idx / 6;     // 0..1023
    const int b = rowblk >> 7, row = rowblk & 127;
    const int which = ny >> 1, half = ny & 1;

    const int tid = threadIdx.x;
    const int wave = tid >> 6, l = tid & 63, col = l & 15, quad = l >> 4;
    const int th = wave >> 1;                   // token half (64 tok)
    const int oq = wave & 1;                    // och quarter
    const int obase = half * 128 + oq * 64;     // och base within `which`

    int orow[4];
    #pragma unroll
    for (int nt = 0; nt < 4; ++nt) {
        const int oo = obase + nt * 16 + col;
        orow[nt] = (oo >> 5) * 96 + which * 32 + (oo & 31);
    }

    const int tc = tid >> 5;
    const int tw = (tid & 31) * 4;
    const float* xbase = x + ((size_t)b * 256 * 128 + row) * 128;

    f32x4 acc[4][4];                            // [nt(och)][mt(tok)]
    #pragma unroll
    for (int i = 0; i < 4; ++i)
        #pragma unroll
        for (int j = 0; j < 4; ++j) acc[i][j] = f32x4{0.f, 0.f, 0.f, 0.f};

    float4 st[8];
    auto stage_load = [&](int c) {
        #pragma unroll
        for (int j = 0; j < 8; ++j)
            st[j] = *(const float4*)(xbase + (size_t)(c * 64 + tc * 8 + j) * 16384 + tw);
    };
    auto stage_write = [&](int buf) {
        u16x8 v0, v1, v2, v3;
        #pragma unroll
        for (int j = 0; j < 8; ++j) {
            v0[j] = f2b(st[j].x);
            v1[j] = f2b(st[j].y);
            v2[j] = f2b(st[j].z);
            v3[j] = f2b(st[j].w);
        }
        const int base7 = tid & 31;
        const int s0 = tc ^ ((base7 ^ (tw + 0)) & 7);
        const int s1 = tc ^ ((base7 ^ (tw + 1)) & 7);
        const int s2 = tc ^ ((base7 ^ (tw + 2)) & 7);
        const int s3 = tc ^ ((base7 ^ (tw + 3)) & 7);
        *(u16x8*)&Xs[buf][(tw + 0) * 64 + (s0 << 3)] = v0;
        *(u16x8*)&Xs[buf][(tw + 1) * 64 + (s1 << 3)] = v1;
        *(u16x8*)&Xs[buf][(tw + 2) * 64 + (s2 << 3)] = v2;
        *(u16x8*)&Xs[buf][(tw + 3) * 64 + (s3 << 3)] = v3;
    };
    auto loadW = [&](int c, bf16x8* bw) {
        #pragma unroll
        for (int kk = 0; kk < 2; ++kk)
            #pragma unroll
            for (int nt = 0; nt < 4; ++nt)
                bw[kk * 4 + nt] = *(const bf16x8*)&qkvw[(size_t)orow[nt] * 256 +
                                                        c * 64 + kk * 32 + quad * 8];
    };
    auto gemm = [&](int buf, const bf16x8* bw) {
        #pragma unroll
        for (int kk = 0; kk < 2; ++kk) {
            const int lchunk = kk * 4 + quad;
            bf16x8 af[4];
            #pragma unroll
            for (int mt = 0; mt < 4; ++mt) {
                const int tok = th * 64 + mt * 16 + col;
                const int slot = lchunk ^ (((tok >> 2) ^ tok) & 7);
                af[mt] = *(const bf16x8*)&Xs[buf][tok * 64 + (slot << 3)];
            }
            #pragma unroll
            for (int nt = 0; nt < 4; ++nt)
                #pragma unroll
                for (int mt = 0; mt < 4; ++mt)
                    acc[nt][mt] = __builtin_amdgcn_mfma_f32_16x16x32_bf16(
                        bw[kk * 4 + nt], af[mt], acc[nt][mt], 0, 0, 0);
        }
    };

    bf16x8 bwA[8], bwB[8];
    stage_load(0);
    loadW(0, bwA);
    stage_write(0);
    __syncthreads();
    #pragma unroll
    for (int c = 0; c < 4; ++c) {
        if (c < 3) {
            stage_load(c + 1);                       // x prefetch (T14)
            loadW(c + 1, (c & 1) ? bwA : bwB);       // weight prefetch
        }
        gemm(c & 1, (c & 1) ? bwB : bwA);
        if (c < 3) stage_write((c + 1) & 1);
        __syncthreads();
    }

    // epilogue: D[och][tok]
    const int hA = obase >> 5;
    f32x4 bqv[4];
    #pragma unroll
    for (int nt = 0; nt < 4; ++nt) {
        const int oo = obase + nt * 16 + quad * 4;
        bqv[nt] = *(const f32x4*)&qkvb[(oo >> 5) * 96 + which * 32 + (oo & 31)];
    }
    #pragma unroll
    for (int mt = 0; mt < 4; ++mt) {
        const int tok = th * 64 + mt * 16 + col;
        const int win = b * 256 + (row >> 3) * 16 + (tok >> 3);
        const int tk = (row & 7) * 8 + (tok & 7);
        float v[4][4];
        #pragma unroll
        for (int nt = 0; nt < 4; ++nt)
            #pragma unroll
            for (int r = 0; r < 4; ++r)
                v[nt][r] = acc[nt][mt][r] + bqv[nt][r];
        if (which < 2) {
            float sA = 0.f, sB = 0.f;
            #pragma unroll
            for (int r = 0; r < 4; ++r) {
                sA += v[0][r] * v[0][r] + v[1][r] * v[1][r];
                sB += v[2][r] * v[2][r] + v[3][r] * v[3][r];
            }
            sA += __shfl_xor(sA, 16, 64);
            sA += __shfl_xor(sA, 32, 64);
            sB += __shfl_xor(sB, 16, 64);
            sB += __shfl_xor(sB, 32, 64);
            const float iA = 1.0f / fmaxf(sqrtf(sA), 1e-12f);
            const float iB = 1.0f / fmaxf(sqrtf(sB), 1e-12f);
            #pragma unroll
            for (int r = 0; r < 4; ++r) {
                v[0][r] *= iA; v[1][r] *= iA;
                v[2][r] *= iB; v[3][r] *= iB;
            }
        }
        #pragma unroll
        for (int nt = 0; nt < 4; ++nt) {
            u16x4 ov;
            #pragma unroll
            for (int r = 0; r < 4; ++r) ov[r] = f2b(v[nt][r]);
            if (which == 2) {
                *(u16x4*)&wv_g[((size_t)win * 64 + tk) * 256 + obase + nt * 16 + quad * 4] = ov;
            } else {
                u16* G = (which == 0) ? gq : gk;
                const int h = hA + (nt >> 1);
                const int d = (nt & 1) * 16 + quad * 4;
                *(u16x4*)&G[((size_t)(win * 8 + h) * 64 + tk) * 32 + d] = ov;
            }
        }
    }
}

// ---------------------------------------------------------------- attn ----
// S^T layout: sacc[mt][nt] = mfma(K,Q) -> D[k][q]; lane holds one q-column's
// 16 k-values -> softmax = in-reg + 2 shuffles. PV packs P^T B-frags straight
// from sacc registers (K-slot permutation pi applied identically to v_t's
// LDS column order), so P never touches LDS. Barrier-free; 1 wave = 1 job.
__global__ __launch_bounds__(256, 3) void k_attn3(
    const u16* __restrict__ gq, const u16* __restrict__ gk,
    const u16* __restrict__ wv_g,
    const float* __restrict__ lsc, const float* __restrict__ biasT,
    u16* __restrict__ wout_g) {
    __shared__ __align__(16) u16 scr[4][2048];  // per wave: v_t only

    const int tid = threadIdx.x;
    const int wave = tid >> 6, l = tid & 63, col = l & 15, quad = l >> 4;
    const int job = blockIdx.x * 4 + wave;
    const int h = job >> 11, win = job & 2047;
    u16* const v_t = scr[wave];  // [32 d][64 pi-slot] swz(d&7)

    // stage V with pi-permuted column order:
    // k=tok -> slot = (k>>5)*32 + ((k>>2)&3)*8 + ((k>>4)&1)*4 + (k&3)
    #pragma unroll
    for (int it = 0; it < 4; ++it) {
        const int idx = it * 64 + l;
        const int tok = idx & 63, dblk = idx >> 6;
        const u16x8 vv = *(const u16x8*)&wv_g[((size_t)win * 64 + tok) * 256 + h * 32 + dblk * 8];
        const int g = (tok >> 5) * 4 + ((tok >> 2) & 3);
        const int jj = ((tok >> 4) & 1) * 4 + (tok & 3);
        #pragma unroll
        for (int j = 0; j < 8; ++j) {
            const int d = dblk * 8 + j;
            v_t[d * 64 + (((g ^ (d & 7)) << 3) | jj)] = vv[j];
        }
    }

    // S^T = K . Q^T (same verified loads as before, operands swapped)
    const u16* const qbp = gq + (size_t)(win * 8 + h) * 2048;
    const u16* const kbp = gk + (size_t)(win * 8 + h) * 2048;
    bf16x8 ak[4], bq[4];
    #pragma unroll
    for (int mt = 0; mt < 4; ++mt)
        ak[mt] = *(const bf16x8*)&kbp[(mt * 16 + col) * 32 + quad * 8];
    #pragma unroll
    for (int nt = 0; nt < 4; ++nt)
        bq[nt] = *(const bf16x8*)&qbp[(nt * 16 + col) * 32 + quad * 8];

    const f32x4 zero4 = {0.f, 0.f, 0.f, 0.f};
    f32x4 sacc[4][4];                 // [mt = k-tile][nt = q-tile]
    #pragma unroll
    for (int mt = 0; mt < 4; ++mt)
        #pragma unroll
        for (int nt = 0; nt < 4; ++nt)
            sacc[mt][nt] = __builtin_amdgcn_mfma_f32_16x16x32_bf16(ak[mt], bq[nt], zero4, 0, 0, 0);

    // softmax per q-column: k per lane = mt*16 + quad*4 + r
    const float ls = expf(fminf(lsc[h], 4.6051701859880914f));
    const float* bT = biasT + h * 4096;
    #pragma unroll
    for (int nt = 0; nt < 4; ++nt) {
        const int q = nt * 16 + col;
        float v[4][4];
        float mx = -1e30f;
        #pragma unroll
        for (int mt = 0; mt < 4; ++mt)
            #pragma unroll
            for (int r = 0; r < 4; ++r) {
                v[mt][r] = sacc[mt][nt][r] * ls + bT[(mt * 16 + quad * 4 + r) * 64 + q];
                mx = fmaxf(mx, v[mt][r]);
            }
        mx = fmaxf(mx, __shfl_xor(mx, 16, 64));
        mx = fmaxf(mx, __shfl_xor(mx, 32, 64));
        float s = 0.f;
        #pragma unroll
        for (int mt = 0; mt < 4; ++mt)
            #pragma unroll
            for (int r = 0; r < 4; ++r) {
                v[mt][r] = expf(v[mt][r] - mx);
                s += v[mt][r];
            }
        s += __shfl_xor(s, 16, 64);
        s += __shfl_xor(s, 32, 64);
        const float inv = 1.0f / s;
        #pragma unroll
        for (int mt = 0; mt < 4; ++mt)
            #pragma unroll
            for (int r = 0; r < 4; ++r)
                sacc[mt][nt][r] = v[mt][r] * inv;
    }

    // PV: D[d][q] = V^T . P^T ; A from v_t (pi-ordered), B packed from sacc.
    f32x4 oacc[2][4];                 // [dt][qt]
    #pragma unroll
    for (int i = 0; i < 2; ++i)
        #pragma unroll
        for (int j = 0; j < 4; ++j) oacc[i][j] = zero4;
    #pragma unroll
    for (int kk = 0; kk < 2; ++kk) {
        bf16x8 av[2];
        #pragma unroll
        for (int dt = 0; dt < 2; ++dt) {
            const int d = dt * 16 + col;
            av[dt] = *(const bf16x8*)&v_t[d * 64 + (((kk * 4 + quad) ^ (d & 7)) << 3)];
        }
        #pragma unroll
        for (int nt = 0; nt < 4; ++nt) {
            union { u16x8 u; bf16x8 b; } pk;
            #pragma unroll
            for (int j = 0; j < 4; ++j) {
                pk.u[j]     = f2b(sacc[kk * 2][nt][j]);
                pk.u[j + 4] = f2b(sacc[kk * 2 + 1][nt][j]);
            }
            #pragma unroll
            for (int dt = 0; dt < 2; ++dt)
                oacc[dt][nt] = __builtin_amdgcn_mfma_f32_16x16x32_bf16(
                    av[dt], pk.b, oacc[dt][nt], 0, 0, 0);
        }
    }
    #pragma unroll
    for (int dt = 0; dt < 2; ++dt)
        #pragma unroll
        for (int qt = 0; qt < 4; ++qt) {
            const int t = qt * 16 + col;
            u16x4 ov;
            #pragma unroll
            for (int r = 0; r < 4; ++r) ov[r] = f2b(oacc[dt][qt][r]);
            *(u16x4*)&wout_g[((size_t)win * 64 + t) * 256 + h * 32 + dt * 16 + quad * 4] = ov;
        }
}

// ---------------------------------------------------------------- proj ----
// R7 verbatim: operand-swapped GEMM, direct float4 stores.
__global__ __launch_bounds__(256, 4) void k_proj(
    const u16* __restrict__ wout_g, const u16* __restrict__ wv_g,
    const float* __restrict__ pe_w, const float* __restrict__ pe_b,
    const u16* __restrict__ pjw, const float* __restrict__ pjb,
    float* __restrict__ out) {
    __shared__ __align__(16) u16 y_s[64 * 256];
    const int win = blockIdx.x;
    const int b = win >> 8;
    const int h0 = ((win >> 4) & 15) * 8;
    const int w0 = (win & 15) * 8;
    const int tid = threadIdx.x;
    const int cg = tid & 31, ch = cg * 8;
    const int psub = tid >> 5;

    float pw[9][8];
    #pragma unroll
    for (int j = 0; j < 8; ++j)
        #pragma unroll
        for (int k = 0; k < 9; ++k) pw[k][j] = pe_w[(ch + j) * 9 + k];
    float pb[8];
    #pragma unroll
    for (int j = 0; j < 8; ++j) pb[j] = pe_b[ch + j];

    for (int it = 0; it < 8; ++it) {
        const int p = it * 8 + psub;
        const int gh = h0 + (p >> 3), gw = w0 + (p & 7);
        float a[8];
        {
            const bf16x8 ov = *(const bf16x8*)&wout_g[((size_t)win * 64 + p) * 256 + ch];
            #pragma unroll
            for (int j = 0; j < 8; ++j) a[j] = b2f((u16)ov[j]) + pb[j];
        }
        #pragma unroll
        for (int dy = -1; dy <= 1; ++dy)
            #pragma unroll
            for (int dx = -1; dx <= 1; ++dx) {
                const int hh = gh + dy, ww2 = gw + dx;
                if (hh < 0 || hh >= 128 || ww2 < 0 || ww2 >= 128) continue;
                const int nwin = b * 256 + (hh >> 3) * 16 + (ww2 >> 3);
                const int ntk = (hh & 7) * 8 + (ww2 & 7);
                const bf16x8 vv = *(const bf16x8*)&wv_g[((size_t)nwin * 64 + ntk) * 256 + ch];
                const int k = (dy + 1) * 3 + (dx + 1);
                #pragma unroll
                for (int j = 0; j < 8; ++j) a[j] += b2f((u16)vv[j]) * pw[k][j];
            }
        u16x8 tmp;
        #pragma unroll
        for (int j = 0; j < 8; ++j) tmp[j] = f2b(a[j]);
        *(u16x8*)&y_s[p * 256 + (((ch >> 3) ^ (p & 7)) << 3)] = tmp;
    }
    __syncthreads();

    const int wave = tid >> 6, l = tid & 63;
    const int col = l & 15, quad = l >> 4;
    const f32x4 zero4 = {0.f, 0.f, 0.f, 0.f};
    f32x4 macc[4][4];                    // [pt(tok)][ot(och)]
    #pragma unroll
    for (int pt = 0; pt < 4; ++pt)
        #pragma unroll
        for (int ot = 0; ot < 4; ++ot) macc[pt][ot] = zero4;
    const int ob = wave * 64;
    for (int kk = 0; kk < 8; ++kk) {
        const int cb = kk * 32 + quad * 8;
        bf16x8 aw[4], by[4];
        #pragma unroll
        for (int ot = 0; ot < 4; ++ot)
            aw[ot] = *(const bf16x8*)&pjw[(size_t)(ob + ot * 16 + col) * 256 + cb];
        #pragma unroll
        for (int pt = 0; pt < 4; ++pt) {
            const int p = pt * 16 + col;
            by[pt] = *(const bf16x8*)&y_s[p * 256 + (((cb >> 3) ^ (p & 7)) << 3)];
        }
        #pragma unroll
        for (int pt = 0; pt < 4; ++pt)
            #pragma unroll
            for (int ot = 0; ot < 4; ++ot)
                macc[pt][ot] = __builtin_amdgcn_mfma_f32_16x16x32_bf16(
                    by[pt], aw[ot], macc[pt][ot], 0, 0, 0);
    }
    #pragma unroll
    for (int ot = 0; ot < 4; ++ot) {
        const int o = ob + ot * 16 + col;
        const float pbv = pjb[o];
        #pragma unroll
        for (int pt = 0; pt < 4; ++pt) {
            const int p0 = pt * 16 + quad * 4;
            float4 ov;
            ov.x = macc[pt][ot][0] + pbv;
            ov.y = macc[pt][ot][1] + pbv;
            ov.z = macc[pt][ot][2] + pbv;
            ov.w = macc[pt][ot][3] + pbv;
            *(float4*)&out[((size_t)(b * 256 + o)) * 16384 +
                           (h0 + (p0 >> 3)) * 128 + w0 + (p0 & 7)] = ov;
        }
    }
}

// -------------------------------------------------------------- launch ----
extern "C" void kernel_launch(void* const* d_in, const int* in_sizes, int n_in,
                              void* d_out, int out_size, void* d_ws, size_t ws_size,
                              hipStream_t stream) {
    const float* x    = (const float*)d_in[0];
    const float* qkvw = (const float*)d_in[1];
    const float* qkvb = (const float*)d_in[2];
    const float* pjw  = (const float*)d_in[3];
    const float* pjb  = (const float*)d_in[4];
    const float* pew  = (const float*)d_in[5];
    const float* peb  = (const float*)d_in[6];
    const float* lsc  = (const float*)d_in[7];
    const float* w1   = (const float*)d_in[8];
    const float* b1   = (const float*)d_in[9];
    const float* w2   = (const float*)d_in[10];

    char* ws = (char*)d_ws;
    u16* wv_b    = (u16*)(ws);                                    // 64 MiB
    u16* wout_b  = (u16*)(ws + (64ull << 20));                    // 64 MiB
    u16* qkvwb   = (u16*)(ws + (128ull << 20));                   // 384 KiB
    u16* pjwb    = (u16*)(ws + (128ull << 20) + 393216);          // 128 KiB
    float* biasT = (float*)(ws + (128ull << 20) + 393216 + 131072); // 128 KiB
    float* bt    = (float*)(ws + (128ull << 20) + 393216 + 262144); // 7.2 KiB

    // q/k scratch lives inside d_out; dead before k_proj overwrites d_out.
    u16* gq = (u16*)d_out;
    u16* gk = gq + 33554432u;

    hipLaunchKernelGGL(k_prep, dim3(768), dim3(256), 0, stream, qkvw, pjw, qkvwb, pjwb);
    hipLaunchKernelGGL(k_cpb,  dim3(1),   dim3(256), 0, stream, w1, b1, w2, bt);
    hipLaunchKernelGGL(k_bias, dim3(16),  dim3(256), 0, stream, bt, biasT);
    hipLaunchKernelGGL(k_qkv,  dim3(6144), dim3(256), 0, stream,
                       x, qkvwb, qkvb, gq, gk, wv_b);
    hipLaunchKernelGGL(k_attn3, dim3(4096), dim3(256), 0, stream,
                       gq, gk, wv_b, lsc, biasT, wout_b);
    hipLaunchKernelGGL(k_proj, dim3(2048), dim3(256), 0, stream,
                       wout_b, wv_b, pew, peb, pjwb, pjb, (float*)d_out);
}